// Round 7
// baseline (342.324 us; speedup 1.0000x reference)
//
#include <hip/hip_runtime.h>
#include <hip/hip_fp16.h>
#include <math.h>

#define NB 4
#define NR 4096
#define NS 48
#define PLANE_ELEMS (65536*32)     // H*W*C per (b,plane) (elements)
#define PLANE_BYTES (PLANE_ELEMS*2) // f16

typedef _Float16 f16x8 __attribute__((ext_vector_type(8)));
typedef float    f32x4 __attribute__((ext_vector_type(4)));

__device__ __forceinline__ float coarse_depth(float cam, int i) {
    float nearv = cam - 0.5f;
    float farv  = cam + 0.5f;
    float t = ((float)i + 0.5f) / 48.0f;
    return nearv + (farv - nearv) * t;
}
__device__ __forceinline__ float softplusf(float x) {
    return fmaxf(x, 0.0f) + __logf(1.0f + __expf(-fabsf(x)));
}
__device__ __forceinline__ float sigmoidf(float x) {
    return 1.0f / (1.0f + __expf(-x));
}
__device__ __forceinline__ unsigned pk16(float a, float b) {
    auto p = __builtin_amdgcn_cvt_pkrtz(a, b);   // __fp16 ext_vector_type(2)
    unsigned u; __builtin_memcpy(&u, &p, 4); return u;
}

// K0: transpose planes [bp][C][H][W] f32 -> [bp][H][W][C] f16 (64B/texel).
// float4 loads, cvt_pkrtz, conflict-free LDS [cpair][x] (pad 264), texel-
// grouped dwordx4 stores. Block 3072 packs w1 into MFMA A-fragment layout.
__global__ __launch_bounds__(256) void k_transpose(const float* __restrict__ src,
                                                   __half* __restrict__ dst,
                                                   const float* __restrict__ w1,
                                                   unsigned* __restrict__ w1frag) {
    if (blockIdx.x == 3072) {
        int t = threadIdx.x;
        for (int f = t; f < 1024; f += 256) {
            int ht = f >> 8, rem = f & 255, lane = rem >> 2, qq = rem & 3;
            int quad = lane >> 4, m = lane & 15;
            int k0 = quad*8 + 2*qq;
            __half lo = __float2half_rn(w1[(k0+0)*64 + ht*16 + m]);
            __half hi = __float2half_rn(w1[(k0+1)*64 + ht*16 + m]);
            w1frag[f] = (unsigned)__half_as_ushort(lo)
                      | ((unsigned)__half_as_ushort(hi) << 16);
        }
        return;
    }
    __shared__ unsigned tile[16*264];     // [cpair][x], pad 264
    int bp = blockIdx.x >> 8;
    int y  = blockIdx.x & 255;
    int t  = threadIdx.x;
    int xb = (t & 63) * 4;                // this thread's 4 x positions
    int cg = t >> 6;                      // channel group 0..3 -> ch 8cg..8cg+7
    const float* s = src + (size_t)bp*PLANE_ELEMS + (size_t)y*256;
    #pragma unroll
    for (int pr = 0; pr < 4; ++pr) {      // channel pair (2c, 2c+1)
        int c = cg*8 + pr*2;
        float4 fa = *reinterpret_cast<const float4*>(s + (size_t)(c+0)*65536 + xb);
        float4 fb = *reinterpret_cast<const float4*>(s + (size_t)(c+1)*65536 + xb);
        int row = (cg*4 + pr) * 264;
        *reinterpret_cast<uint2*>(&tile[row + xb]) =
            make_uint2(pk16(fa.x, fb.x), pk16(fa.y, fb.y));
        *reinterpret_cast<uint2*>(&tile[row + xb + 2]) =
            make_uint2(pk16(fa.z, fb.z), pk16(fa.w, fb.w));
    }
    __syncthreads();
    unsigned* d = reinterpret_cast<unsigned*>(dst + ((size_t)bp*65536 + (size_t)y*256)*32);
    #pragma unroll
    for (int q = 0; q < 4; ++q) {
        uint4 u;
        u.x = tile[(q*4+0)*264 + t];
        u.y = tile[(q*4+1)*264 + t];
        u.z = tile[(q*4+2)*264 + t];
        u.w = tile[(q*4+3)*264 + t];
        *reinterpret_cast<uint4*>(&d[t*16 + q*4]) = u;
    }
}

// K1/K3: plane sampling + decoder MLP (MFMA). One block = 256 points.
// SGPR plane base (b uniform from blockIdx) + 32-bit byte offsets -> saddr
// loads; w1 GEMV on matrix pipe; wave-local gather->MLP handoff.
__global__ __launch_bounds__(256, 5) void k_sample_mlp(
    const __half* __restrict__ planesT,
    const float* __restrict__ orig, const float* __restrict__ dirs,
    const unsigned* __restrict__ w1frag, const float* __restrict__ b1,
    const float* __restrict__ w2, const float* __restrict__ b2,
    const float* __restrict__ dfine,
    float* __restrict__ colors, float* __restrict__ sigmas,
    int mode)
{
    __shared__ unsigned desc[256*12];   // [pt][12]: f16 weight<<16 | u16 texel
    __shared__ unsigned featT[256*16];  // [pt][16 c-pairs], swizzled
    __shared__ float b1s[64];
    __shared__ float w2s[256];          // row j = w2[j][0..3]

    int tid = threadIdx.x;
    int pid = blockIdx.x * 256 + tid;
    int rid = pid / 48;
    int s   = pid - rid*48;
    int b   = blockIdx.x / 768;         // wave-uniform batch (768 blocks/batch)

    // ---- phase 0: 12 packed tap descriptors for this thread's point ----
    float ox = orig[rid*3+0], oy = orig[rid*3+1], oz = orig[rid*3+2];
    float dxv = dirs[rid*3+0], dyv = dirs[rid*3+1], dzv = dirs[rid*3+2];
    float depth;
    if (mode == 0) {
        float cam = sqrtf(ox*ox + oy*oy + oz*oz);
        depth = coarse_depth(cam, s);
    } else {
        depth = dfine[(size_t)rid*48 + s];
    }
    float cx = ox + depth*dxv;
    float cy = oy + depth*dyv;
    float cz = oz + depth*dzv;
    float us[3] = {cx, cz, cy};   // p0 (x,y), p1 (z,x), p2 (y,z)
    float vs[3] = {cy, cx, cz};
    unsigned dpk[12];
    #pragma unroll
    for (int pl = 0; pl < 3; ++pl) {
        float xg = (us[pl] + 1.0f) * 0.5f * 256.0f - 0.5f;
        float yg = (vs[pl] + 1.0f) * 0.5f * 256.0f - 0.5f;
        float x0f = floorf(xg), y0f = floorf(yg);
        float wx = xg - x0f, wy = yg - y0f;
        int x0 = (int)x0f, y0 = (int)y0f;
        float tw[4] = {(1.0f-wx)*(1.0f-wy), wx*(1.0f-wy), (1.0f-wx)*wy, wx*wy};
        #pragma unroll
        for (int t4 = 0; t4 < 4; ++t4) {
            int xi = x0 + (t4 & 1);
            int yi = y0 + (t4 >> 1);
            bool valid = (xi >= 0) && (xi < 256) && (yi >= 0) && (yi < 256);
            int xc = min(max(xi, 0), 255);
            int yc = min(max(yi, 0), 255);
            float wv = valid ? tw[t4] : 0.0f;
            dpk[pl*4+t4] = ((unsigned)__half_as_ushort(__float2half_rn(wv)) << 16)
                         | (unsigned)(yc*256 + xc);
        }
    }
    #pragma unroll
    for (int q = 0; q < 6; ++q)
        *reinterpret_cast<uint2*>(&desc[tid*12 + 2*q]) = make_uint2(dpk[2*q], dpk[2*q+1]);
    if (tid < 64) {
        b1s[tid] = b1[tid];
        *reinterpret_cast<float4*>(&w2s[tid*4]) =
            *reinterpret_cast<const float4*>(&w2[tid*4]);
    }
    __syncthreads();

    // ---- phase 1: per-wave gather, 8 lanes/point, saddr+voff loads ----
    int lane = tid & 63, wbase = tid & 192;
    int g8 = lane >> 3, sub = lane & 7, c0 = sub*4;
    const char* pb = reinterpret_cast<const char*>(planesT) + (size_t)(b*3)*PLANE_BYTES;
    const __half2 inv3h = __float2half2_rn(1.0f/3.0f);
    unsigned laneoff = (unsigned)(c0 << 1);
    #pragma unroll 2
    for (int it = 0; it < 8; ++it) {
        int pp = wbase + it*8 + g8;
        __half2 a01 = __float2half2_rn(0.0f);
        __half2 a23 = __float2half2_rn(0.0f);
        #pragma unroll
        for (int h6 = 0; h6 < 2; ++h6) {
            unsigned dd[6];
            #pragma unroll
            for (int q = 0; q < 3; ++q) {
                uint2 pr = *reinterpret_cast<const uint2*>(&desc[pp*12 + h6*6 + 2*q]);
                dd[2*q] = pr.x; dd[2*q+1] = pr.y;
            }
            uint2 v[6]; __half2 wv[6];
            #pragma unroll
            for (int q = 0; q < 6; ++q) {
                int tp = h6*6 + q;
                unsigned voff = ((dd[q] & 0xFFFFu) << 6) + laneoff
                              + (unsigned)((tp>>2) * PLANE_BYTES);
                wv[q] = __half2half2(__ushort_as_half((unsigned short)(dd[q] >> 16)));
                v[q] = *reinterpret_cast<const uint2*>(pb + voff);
            }
            #pragma unroll
            for (int q = 0; q < 6; ++q) {
                __half2 v01, v23;
                __builtin_memcpy(&v01, &v[q].x, 4);
                __builtin_memcpy(&v23, &v[q].y, 4);
                a01 = __hfma2(wv[q], v01, a01);
                a23 = __hfma2(wv[q], v23, a23);
            }
        }
        a01 = __hmul2(a01, inv3h);
        a23 = __hmul2(a23, inv3h);
        unsigned u01, u23;
        __builtin_memcpy(&u01, &a01, 4);
        __builtin_memcpy(&u23, &a23, 4);
        int base = pp*16 + (((sub>>1) ^ (pp&3)) << 2) + ((sub&1) << 1);
        *reinterpret_cast<uint2*>(&featT[base]) = make_uint2(u01, u23);
    }
    // wave-local LDS handoff: DS in-order per wave
    asm volatile("s_waitcnt lgkmcnt(0)" ::: "memory");

    // ---- phase 2: MLP via MFMA f32_16x16x32_f16 ----
    int w    = tid >> 6;
    int quad = lane >> 4;
    int n    = lane & 15;
    f16x8 af[4];
    {
        const uint4* wf = reinterpret_cast<const uint4*>(w1frag);
        #pragma unroll
        for (int ht = 0; ht < 4; ++ht) {
            uint4 u = wf[ht*64 + lane];
            __builtin_memcpy(&af[ht], &u, 16);
        }
    }
    #pragma unroll
    for (int p = 0; p < 4; ++p) {
        int ptile = w*4 + p;
        int pt    = ptile*16 + n;
        uint4 bu = *reinterpret_cast<const uint4*>(
            &featT[pt*16 + ((quad ^ (pt&3)) << 2)]);
        f16x8 bf;
        __builtin_memcpy(&bf, &bu, 16);
        float o0=0.f, o1=0.f, o2=0.f, o3=0.f;
        #pragma unroll
        for (int ht = 0; ht < 4; ++ht) {
            f32x4 acc = {0.f, 0.f, 0.f, 0.f};
            acc = __builtin_amdgcn_mfma_f32_16x16x32_f16(af[ht], bf, acc, 0, 0, 0);
            float4 bb = *reinterpret_cast<const float4*>(&b1s[ht*16 + quad*4]);
            float bbv[4] = {bb.x, bb.y, bb.z, bb.w};
            #pragma unroll
            for (int r = 0; r < 4; ++r) {
                float hv = softplusf(acc[r] + bbv[r]);
                float4 wr = *reinterpret_cast<const float4*>(
                    &w2s[(ht*16 + quad*4 + r)*4]);
                o0 = fmaf(hv, wr.x, o0);
                o1 = fmaf(hv, wr.y, o1);
                o2 = fmaf(hv, wr.z, o2);
                o3 = fmaf(hv, wr.w, o3);
            }
        }
        o0 += __shfl_xor(o0, 16); o0 += __shfl_xor(o0, 32);
        o1 += __shfl_xor(o1, 16); o1 += __shfl_xor(o1, 32);
        o2 += __shfl_xor(o2, 16); o2 += __shfl_xor(o2, 32);
        o3 += __shfl_xor(o3, 16); o3 += __shfl_xor(o3, 32);
        int pid2 = blockIdx.x*256 + ptile*16 + n;
        int rid2 = pid2 / 48;
        int s2   = pid2 - rid2*48;
        int slot = rid2*96 + (mode ? 48 + s2 : s2);
        if (quad == 0) {
            sigmas[slot] = 10.0f * softplusf(-10.0f * (o0 + b2[0]));
        } else {
            float oc = (quad == 1) ? o1 : (quad == 2 ? o2 : o3);
            colors[(size_t)slot*3 + (quad-1)] =
                sigmoidf(oc + b2[quad]) * 1.002f - 0.001f;
        }
    }
}

// K2: per-ray coarse weights -> blurred pdf -> inverse-CDF fine depths.
__global__ __launch_bounds__(64) void k_importance(
    const float* __restrict__ orig, const float* __restrict__ sigmas,
    float* __restrict__ dfine)
{
    __shared__ float tile[64*49];
    int t  = threadIdx.x;
    int r0 = blockIdx.x * 64;
    for (int it = 0; it < 48; ++it) {
        int l  = it*64 + t;
        int ri = l / 48;
        int i  = l - ri*48;
        tile[ri*49 + i] = sigmas[(size_t)(r0+ri)*96 + i];
    }
    __syncthreads();
    int rid = r0 + t;
    float ox = orig[rid*3+0], oy = orig[rid*3+1], oz = orig[rid*3+2];
    float cam = sqrtf(ox*ox + oy*oy + oz*oz);

    float w[47];
    float T = 1.0f;
    float sp_ = tile[t*49 + 0];
    float dprev = coarse_depth(cam, 0);
    #pragma unroll
    for (int i = 0; i < 47; ++i) {
        float sc = tile[t*49 + i + 1];
        float dnext = coarse_depth(cam, i+1);
        float delta = dnext - dprev;
        float dm = 0.5f*(sp_ + sc);
        float a = 1.0f - __expf(-delta*dm);
        w[i] = a * T;
        T *= (1.0f - a + 1e-10f);
        sp_ = sc; dprev = dnext;
    }
    float Ssum = 0.0f;
    #pragma unroll
    for (int m = 0; m < 45; ++m) {
        float wm1 = fmaxf(w[m],   w[m+1]);
        float wm2 = fmaxf(w[m+1], w[m+2]);
        float wq = (0.5f*(wm1 + wm2) + 0.01f) + 1e-5f;
        tile[t*49 + m] = wq;
        Ssum += wq;
    }
    int idx = 1;
    float cprev = 0.0f;
    float ccur  = tile[t*49 + 0] / Ssum;
    for (int k = 0; k < 48; ++k) {
        float u = (float)k * (1.0f/47.0f);
        while (idx < 46 && ccur <= u) {
            cprev = ccur;
            idx++;
            if (idx < 46) ccur += tile[t*49 + (idx-1)] / Ssum;
        }
        int below = idx - 1;
        int above = min(idx, 45);
        float cb = cprev;
        float ca = (idx < 46) ? ccur : cprev;
        float bb = 0.5f*(coarse_depth(cam, below) + coarse_depth(cam, below+1));
        float ba = 0.5f*(coarse_depth(cam, above) + coarse_depth(cam, above+1));
        float d_ = ca - cb;
        float den = (d_ < 1e-5f) ? 1.0f : d_;
        dfine[(size_t)rid*48 + k] = bb + (u - cb)/den * (ba - bb);
    }
}

// K4: stable merge + final ray march; sample data staged coalesced into LDS.
__global__ __launch_bounds__(64) void k_final(
    const float* __restrict__ orig,
    const float* __restrict__ colors, const float* __restrict__ sigmas,
    const float* __restrict__ dfine, float* __restrict__ out)
{
    __shared__ float scol[32*289];
    __shared__ float ssig[32*97];
    __shared__ float sdf [32*49];
    int t  = threadIdx.x;
    int r0 = blockIdx.x * 32;

    {
        const float4* src = reinterpret_cast<const float4*>(colors + (size_t)r0*288);
        for (int q = t; q < 2304; q += 64) {
            float4 v = src[q];
            int e = q*4, row = e/288, col = e - row*288;
            scol[row*289+col+0] = v.x; scol[row*289+col+1] = v.y;
            scol[row*289+col+2] = v.z; scol[row*289+col+3] = v.w;
        }
    }
    {
        const float4* src = reinterpret_cast<const float4*>(sigmas + (size_t)r0*96);
        for (int q = t; q < 768; q += 64) {
            float4 v = src[q];
            int e = q*4, row = e/96, col = e - row*96;
            ssig[row*97+col+0] = v.x; ssig[row*97+col+1] = v.y;
            ssig[row*97+col+2] = v.z; ssig[row*97+col+3] = v.w;
        }
    }
    {
        const float4* src = reinterpret_cast<const float4*>(dfine + (size_t)r0*48);
        for (int q = t; q < 384; q += 64) {
            float4 v = src[q];
            int e = q*4, row = e/48, col = e - row*48;
            sdf[row*49+col+0] = v.x; sdf[row*49+col+1] = v.y;
            sdf[row*49+col+2] = v.z; sdf[row*49+col+3] = v.w;
        }
    }
    __syncthreads();
    if (t >= 32) return;

    int rid = r0 + t;
    float ox = orig[rid*3+0], oy = orig[rid*3+1], oz = orig[rid*3+2];
    float cam = sqrtf(ox*ox + oy*oy + oz*oz);
    int i = 0, j = 0;
    float T = 1.0f, rgb0=0.f, rgb1=0.f, rgb2=0.f, dep=0.f, wsum=0.f;
    float dprev=0.f, sprev=0.f, cp0=0.f, cp1=0.f, cp2=0.f;
    for (int m = 0; m < 96; ++m) {
        float dc = (i < 48) ? coarse_depth(cam, i) : 3.4e38f;
        float df = (j < 48) ? sdf[t*49 + j] : 3.4e38f;
        bool takec = dc <= df;                  // stable: coarse wins ties
        int slot = takec ? i : 48 + j;
        float dcur = takec ? dc : df;
        if (takec) ++i; else ++j;
        float sc = ssig[t*97 + slot];
        float c0 = scol[t*289 + slot*3+0];
        float c1 = scol[t*289 + slot*3+1];
        float c2 = scol[t*289 + slot*3+2];
        if (m > 0) {
            float delta = dcur - dprev;
            float dm = 0.5f*(sprev + sc);
            float zm = 0.5f*(dprev + dcur);
            float a = 1.0f - __expf(-delta*dm);
            float wgt = a * T;
            T *= (1.0f - a + 1e-10f);
            rgb0 += wgt*0.5f*(cp0 + c0);
            rgb1 += wgt*0.5f*(cp1 + c1);
            rgb2 += wgt*0.5f*(cp2 + c2);
            dep  += wgt*zm;
            wsum += wgt;
        }
        dprev = dcur; sprev = sc; cp0 = c0; cp1 = c1; cp2 = c2;
    }
    out[rid*3+0] = rgb0;
    out[rid*3+1] = rgb1;
    out[rid*3+2] = rgb2;
    out[16384*3 + rid] = dep;
    out[16384*4 + rid] = wsum;
}

extern "C" void kernel_launch(void* const* d_in, const int* in_sizes, int n_in,
                              void* d_out, int out_size, void* d_ws, size_t ws_size,
                              hipStream_t stream)
{
    const float* planes = (const float*)d_in[0];
    const float* orig   = (const float*)d_in[1];
    const float* dirs   = (const float*)d_in[2];
    const float* w1     = (const float*)d_in[3];
    const float* b1     = (const float*)d_in[4];
    const float* w2     = (const float*)d_in[5];
    const float* b2     = (const float*)d_in[6];
    float* out = (float*)d_out;

    float* ws = (float*)d_ws;
    size_t n_sig = (size_t)NB*NR*96;
    size_t n_col = n_sig*3;
    size_t n_df  = (size_t)NB*NR*48;
    float*  sig     = ws;
    float*  col     = sig + n_sig;
    float*  dfin    = col + n_col;
    __half* planesT = (__half*)(dfin + n_df);              // 8B-aligned
    unsigned* w1frag = (unsigned*)(planesT + (size_t)12*PLANE_ELEMS);

    k_transpose<<<3073, 256, 0, stream>>>(planes, planesT, w1, w1frag);
    k_sample_mlp<<<3072, 256, 0, stream>>>(planesT, orig, dirs,
                                           w1frag, b1, w2, b2, dfin, col, sig, 0);
    k_importance<<<256, 64, 0, stream>>>(orig, sig, dfin);
    k_sample_mlp<<<3072, 256, 0, stream>>>(planesT, orig, dirs,
                                           w1frag, b1, w2, b2, dfin, col, sig, 1);
    k_final<<<512, 64, 0, stream>>>(orig, col, sig, dfin, out);
}